// Round 4
// baseline (1350.584 us; speedup 1.0000x reference)
//
#include <hip/hip_runtime.h>
#include <hip/hip_cooperative_groups.h>
#include <math.h>

namespace cg = cooperative_groups;

#define BB 4
#define NX 4096
#define NYP 8192
#define GG 4096
#define WIDTH 32
#define SS 16
#define PI_F 3.14159265358979323846f
#define CB 256
#define CT 256

__device__ __forceinline__ float gelu_exact(float v) {
    return 0.5f * v * (1.0f + erff(v * 0.70710678118654752f));
}

// ---------------- embed split-K partials: 3 chunks x 1024 g-groups ----------------
__global__ __launch_bounds__(256) void k_embed_part(
    const float* __restrict__ x, const float* __restrict__ loc,
    const float* __restrict__ We1, const float* __restrict__ We2,
    float* __restrict__ part)
{
    int blk = blockIdx.x;
    int chunk = blk >> 10;       // 0..2
    int ggrp  = blk & 1023;
    int gbase = ggrp * 4;
    int t = threadIdx.x;
    float acc[32];
    #pragma unroll
    for (int k = 0; k < 32; ++k) acc[k] = 0.f;

    if (chunk == 0) {
        for (int n4 = t; n4 < 1024; n4 += 256) {
            float4 xb[4];
            #pragma unroll
            for (int b = 0; b < 4; ++b) xb[b] = ((const float4*)(x + (size_t)b * NX))[n4];
            #pragma unroll
            for (int r = 0; r < 4; ++r) {
                float4 w = ((const float4*)(We1 + (size_t)(gbase + r) * NX))[n4];
                #pragma unroll
                for (int b = 0; b < 4; ++b)
                    acc[r*4+b] += w.x*xb[b].x + w.y*xb[b].y + w.z*xb[b].z + w.w*xb[b].w;
            }
        }
    } else {
        int n0 = (chunk - 1) * 1024;
        for (int n4 = n0 + t; n4 < n0 + 1024; n4 += 256) {
            float4 p0[4], p1[4];
            #pragma unroll
            for (int b = 0; b < 4; ++b) {
                const float4* lb = (const float4*)(loc + (size_t)b * NYP * 2);
                p0[b] = lb[n4*2]; p1[b] = lb[n4*2+1];
            }
            #pragma unroll
            for (int r = 0; r < 4; ++r) {
                float4 w = ((const float4*)(We2 + (size_t)(gbase + r) * NYP))[n4];
                #pragma unroll
                for (int b = 0; b < 4; ++b) {
                    acc[r*4+b]      += w.x*p0[b].x + w.y*p0[b].z + w.z*p1[b].x + w.w*p1[b].z;
                    acc[16 + r*4+b] += w.x*p0[b].y + w.y*p0[b].w + w.z*p1[b].y + w.w*p1[b].w;
                }
            }
        }
    }
    #pragma unroll
    for (int k = 0; k < 32; ++k)
        for (int off = 32; off > 0; off >>= 1) acc[k] += __shfl_down(acc[k], off);
    __shared__ float red[4][32];
    int wave = t >> 6, lane = t & 63;
    if (lane == 0) {
        #pragma unroll
        for (int k = 0; k < 32; ++k) red[wave][k] = acc[k];
    }
    __syncthreads();
    if (t < 32) {
        float v = red[0][t] + red[1][t] + red[2][t] + red[3][t];
        int base = (chunk == 0) ? 0 : (chunk == 1 ? 16 : 48);
        if (chunk != 0 || t < 16) part[ggrp * 80 + base + t] = v;
    }
}

// ---------------- cooperative mega-kernel: combine + 4 FNO layers + NU path + head ----------------
struct CoopArgs {
    const float *part, *be1, *be2, *Wfc0, *bfc0;
    const float *cw1, *cw2, *wpt, *wptb;
    const float *nw1, *nw2, *nuw, *nub;
    const float *loc, *Wfc1, *bfc1, *Wfc2, *bfc2;
    const int *ind, *sep;
    float *bufA, *bufB, *s1u, *xfg, *sofg, *Fmb, *im1g, *im2g, *q, *xnu;
};

__global__ __launch_bounds__(256, 2) void k_coop(CoopArgs A)
{
    cg::grid_group grid = cg::this_grid();
    const int t = threadIdx.x;
    const int tid = blockIdx.x * CT + t;
    const int NT = gridDim.x * CT;   // 65536
    __shared__ __align__(16) float smem[3328];

    // ---- Stage 0: embed combine (partials -> h0 in bufA) ----
    for (int task = tid; task < 131072; task += NT) {
        int g = task & 4095, w = task >> 12;
        const float* P = A.part + (g >> 2) * 80;
        int r4 = (g & 3) * 4;
        float w0 = A.Wfc0[w*3], w1 = A.Wfc0[w*3+1], w2 = A.Wfc0[w*3+2], bb = A.bfc0[w];
        float be1g = A.be1[g], be2g = A.be2[g];
        #pragma unroll
        for (int b = 0; b < 4; ++b) {
            float xe = P[r4 + b] + be1g;
            float l0 = P[16 + r4 + b] + P[48 + r4 + b] + be2g;
            float l1 = P[32 + r4 + b] + P[64 + r4 + b] + be2g;
            A.bufA[(size_t)(b * 32 + w) * 4096 + g] = xe * w0 + l0 * w1 + l1 * w2 + bb;
        }
    }
    grid.sync();

    const float* hin = A.bufA;
    float* hout = A.bufB;
    for (int l = 0; l < 4; ++l) {
        const float* w1p = A.cw1 + (size_t)l * 16384;
        const float* w2p = A.cw2 + (size_t)l * 16384;

        // ---- Stage A: row DFT (y -> ky 0..7), LDS-staged ----
        {
            float2* twin = (float2*)smem;            // [ky*65+y], 520 float2
            float* sh = smem + 1040;                 // [lrow*65+y], 32*65
            for (int i = t; i < 512; i += CT) {
                int ky = i >> 6, y = i & 63;
                float s, c; sincosf(-2.f * PI_F * (float)(ky * y) / 64.f, &s, &c);
                twin[ky * 65 + y] = make_float2(c, s);
            }
            __syncthreads();
            for (int cb = blockIdx.x; cb < 256; cb += gridDim.x) {
                const float* src = hin + (size_t)cb * 2048;
                for (int i = t; i < 2048; i += CT) sh[(i >> 6) * 65 + (i & 63)] = src[i];
                __syncthreads();
                int ky = t & 7, lrow = t >> 3;
                const float* row = sh + lrow * 65;
                float sr = 0.f, si = 0.f;
                for (int y = 0; y < 64; ++y) {
                    float2 cs = twin[ky * 65 + y];
                    float v = row[y];
                    sr += v * cs.x; si += v * cs.y;
                }
                int grow = cb * 32 + lrow;
                ((float2*)A.s1u)[grow * 8 + ky] = make_float2(sr, si);
                __syncthreads();
            }
        }
        grid.sync();

        // ---- Stage B: col DFT (x -> kx, 16 modes) ----
        for (int task = tid; task < 16384; task += NT) {
            int bc = task >> 7, kxi = (task >> 3) & 15, ky = task & 7;
            int kx = (kxi < 8) ? kxi : kxi - 16;
            float ss, sc; sincosf(-2.f * PI_F * (float)kx / 64.f, &ss, &sc);
            float cr = 1.f, ci = 0.f, ar = 0.f, ai = 0.f;
            const float2* s1 = (const float2*)A.s1u + (size_t)bc * 512 + ky;
            for (int xx = 0; xx < 64; ++xx) {
                float2 v = s1[xx * 8];
                ar += v.x * cr - v.y * ci;
                ai += v.x * ci + v.y * cr;
                float nr = cr * sc - ci * ss; ci = cr * ss + ci * sc; cr = nr;
            }
            ((float2*)A.xfg)[task] = make_float2(ar, ai);
        }
        grid.sync();

        // ---- Stage C: channel mix ----
        for (int task = tid; task < 16384; task += NT) {
            int b = task >> 12, o = (task >> 7) & 31, kxi = (task >> 3) & 15, ky = task & 7;
            const float* w = (kxi < 8) ? w1p : w2p;
            int kxw = kxi & 7;
            const float2* xf = (const float2*)A.xfg + (size_t)b * 4096 + kxi * 8 + ky;
            float ar = 0.f, ai = 0.f;
            for (int i = 0; i < 32; ++i) {
                float2 xv = xf[i * 128];
                const float* wp = w + (((size_t)(i * 32 + o) * 8 + kxw) * 8 + ky) * 2;
                float wr = wp[0], wi = wp[1];
                ar += xv.x * wr - xv.y * wi;
                ai += xv.x * wi + xv.y * wr;
            }
            ((float2*)A.sofg)[task] = make_float2(ar, ai);
        }
        grid.sync();

        // ---- Stage E: inverse x (redundant per 16-thread row group) + irfft y + pointwise + gelu ----
        {
            int do_g = (l < 3);
            const float* wptl = A.wpt + l * 1024;
            for (int task = tid; task < 131072; task += NT) {
                int rt = task >> 4, yc = task & 15;
                int b = rt >> 11, o = (rt >> 6) & 31, xx = rt & 63;
                int y0 = yc * 4;
                float str[8], sti[8];
                #pragma unroll
                for (int k = 0; k < 8; ++k) { str[k] = 0.f; sti[k] = 0.f; }
                float th = 2.f * PI_F * (float)xx / 64.f;
                float sst, sct; sincosf(th, &sst, &sct);
                const float2* sof = (const float2*)A.sofg + (size_t)(b * 32 + o) * 128;
                float cr = 1.f, ci = 0.f;
                for (int kxi = 0; kxi < 16; ++kxi) {
                    if (kxi == 8) { float s8, c8; sincosf(-8.f * th, &s8, &c8); cr = c8; ci = s8; }
                    #pragma unroll
                    for (int ky = 0; ky < 8; ++ky) {
                        float2 v = sof[kxi * 8 + ky];
                        str[ky] += v.x * cr - v.y * ci;
                        sti[ky] += v.x * ci + v.y * cr;
                    }
                    float nr = cr * sct - ci * sst; ci = cr * sst + ci * sct; cr = nr;
                }
                float pw[4] = {0.f, 0.f, 0.f, 0.f};
                const float* hb = hin + (size_t)b * 32 * 4096 + xx * 64 + y0;
                for (int c = 0; c < 32; ++c) {
                    float wc = wptl[o * 32 + c];
                    float4 hv = *((const float4*)(hb + (size_t)c * 4096));
                    pw[0] += wc * hv.x; pw[1] += wc * hv.y; pw[2] += wc * hv.z; pw[3] += wc * hv.w;
                }
                float wb = A.wptb[l * 32 + o];
                float outv[4];
                #pragma unroll
                for (int yy = 0; yy < 4; ++yy) {
                    int y = y0 + yy;
                    float sy1, cy1; sincosf(2.f * PI_F * (float)y / 64.f, &sy1, &cy1);
                    float ck = cy1, sk = sy1;
                    float spec = str[0];
                    #pragma unroll
                    for (int ky = 1; ky < 8; ++ky) {
                        spec += 2.f * (str[ky] * ck - sti[ky] * sk);
                        float nc = ck * cy1 - sk * sy1;
                        sk = ck * sy1 + sk * cy1; ck = nc;
                    }
                    spec *= (1.f / 4096.f);
                    float v = spec + pw[yy] + wb;
                    if (do_g) v = gelu_exact(v);
                    outv[yy] = v;
                }
                *((float4*)(hout + (size_t)(b * 32 + o) * 4096 + xx * 64 + y0)) =
                    make_float4(outv[0], outv[1], outv[2], outv[3]);
            }
        }
        grid.sync();
        { const float* tp = hin; hin = hout; hout = (float*)tp; }
    }
    // hin = final trunk activation h4

    // ---- Stage A2: row DFT 65-pt (y -> bbi 0..8, freq bbi-8) ----
    for (int task = tid; task < 73728; task += NT) {
        int rt = task / 9, bbi = task % 9;
        float f = (float)(bbi - 8);
        float ss, sc; sincosf(-2.f * PI_F * f / 65.f, &ss, &sc);
        float cr = 1.f, ci = 0.f, ar = 0.f, ai = 0.f;
        const float* row = hin + (size_t)rt * 64;
        for (int y = 0; y < 64; ++y) {
            float v = row[y];
            ar += v * cr; ai += v * ci;
            float nr = cr * sc - ci * ss; ci = cr * ss + ci * sc; cr = nr;
        }
        ((float2*)A.s1u)[task] = make_float2(ar, ai);
    }
    grid.sync();

    // ---- Stage B2: col DFT 65-pt (xx -> a 0..16, freq a-8), scale 1/65 ----
    for (int task = tid; task < 19584; task += NT) {
        int bc = task / 153, rem = task % 153, a = rem / 9, bbi = rem % 9;
        float f = (float)(a - 8);
        float ss, sc; sincosf(-2.f * PI_F * f / 65.f, &ss, &sc);
        float cr = 1.f, ci = 0.f, ar = 0.f, ai = 0.f;
        const float2* s1 = (const float2*)A.s1u + (size_t)bc * 576 + bbi;
        for (int xx = 0; xx < 64; ++xx) {
            float2 v = s1[xx * 9];
            ar += v.x * cr - v.y * ci;
            ai += v.x * ci + v.y * cr;
            float nr = cr * sc - ci * ss; ci = cr * ss + ci * sc; cr = nr;
        }
        ((float2*)A.Fmb)[task] = make_float2(ar * (1.f / 65.f), ai * (1.f / 65.f));
    }
    grid.sync();

    // ---- Stage IMG1 (mode mix -> im1/im2) + HEAD (q) ----
    for (int task = tid; task < 147456; task += NT) {
        if (task < 16384) {
            if (task < 8704) {            // im1: 64 bs x 136
                int bs = task / 136, idx = task % 136;
                int b = bs >> 4, s = bs & 15;
                int xx = idx >> 3, yi = idx & 7;
                float ar = 0.f, ai = 0.f;
                for (int i = 0; i < 32; ++i) {
                    const float2 fv = ((const float2*)A.Fmb)[(size_t)(b * 32 + i) * 153 + xx * 9 + yi];
                    const float* wp = A.nw1 + (((size_t)(i * 16 + s) * 17 + xx) * 8 + yi) * 2;
                    float wr = wp[0], wi = wp[1];
                    ar += fv.x * wr - fv.y * wi;
                    ai += fv.x * wi + fv.y * wr;
                }
                ((float2*)A.im1g)[task] = make_float2(ar, ai);
            } else if (task < 9280) {     // im2: 64 bs x 9
                int u = task - 8704;
                int bs = u / 9, k = u % 9;
                int b = bs >> 4, s = bs & 15;
                float ar = 0.f, ai = 0.f;
                for (int i = 0; i < 32; ++i) {
                    const float2 fv = ((const float2*)A.Fmb)[(size_t)(b * 32 + i) * 153 + k * 9 + 8];
                    const float* wp = A.nw2 + ((size_t)(i * 16 + s) * 9 + k) * 2;
                    float wr = wp[0], wi = wp[1];
                    ar += fv.x * wr - fv.y * wi;
                    ai += fv.x * wi + fv.y * wr;
                }
                ((float2*)A.im2g)[u] = make_float2(ar, ai);
            }
        } else {                          // head: 16384 g x 8-way j-split
            int ht = task - 16384;
            int gq = ht >> 3, prt = ht & 7;
            int b = gq >> 12, g = gq & 4095;
            float hv[32];
            #pragma unroll
            for (int c = 0; c < 32; ++c) hv[c] = hin[(size_t)(b * 32 + c) * 4096 + g];
            float acc = 0.f;
            for (int jj = 0; jj < 16; ++jj) {
                int j = prt * 16 + jj;
                float z = A.bfc1[j];
                const float* wr = A.Wfc1 + j * 32;
                #pragma unroll
                for (int c = 0; c < 32; ++c) z += wr[c] * hv[c];
                acc += A.Wfc2[j] * gelu_exact(z);
            }
            acc += __shfl_down(acc, 4, 8);
            acc += __shfl_down(acc, 2, 8);
            acc += __shfl_down(acc, 1, 8);
            if (prt == 0) A.q[gq] = acc + A.bfc2[0];
        }
    }
    grid.sync();

    // ---- Stage NUDFT: 64 (b,s) x 8 point-chunks ----
    for (int u = blockIdx.x; u < 512; u += gridDim.x) {
        int bs = u & 63, chunk = u >> 6;
        int b = bs >> 4, s = bs & 15;
        float2* img = (float2*)smem;                 // 289 float2
        float* r0 = smem + 578; float* r1 = r0 + 256; float* r2 = r1 + 256; float* r3 = r2 + 256;
        const float2* i1 = (const float2*)A.im1g + (size_t)bs * 136;
        const float2* i2 = (const float2*)A.im2g + (size_t)bs * 9;
        for (int task = t; task < 289; task += CT) {
            int xx = task / 17, y = task % 17;
            float2 v;
            if (y < 8)       v = i1[xx * 8 + y];
            else if (y > 8)  { float2 w = i1[(16 - xx) * 8 + (16 - y)]; v = make_float2(w.x, -w.y); }
            else {
                if (xx < 8)       v = i2[xx];
                else if (xx == 8) v = make_float2(i2[8].x, 0.f);
                else              { float2 w = i2[16 - xx]; v = make_float2(w.x, -w.y); }
            }
            img[task] = v;
        }
        int j0 = A.sep[b * 17 + s], j1 = A.sep[b * 17 + s + 1];
        float mn0 = 1e30f, mn1 = 1e30f, mx0 = -1e30f, mx1 = -1e30f;
        for (int j = j0 + t; j < j1; j += CT) {
            int p = A.ind[b * NYP + j];
            float l0 = A.loc[((size_t)b * NYP + p) * 2];
            float l1 = A.loc[((size_t)b * NYP + p) * 2 + 1];
            mn0 = fminf(mn0, l0); mx0 = fmaxf(mx0, l0);
            mn1 = fminf(mn1, l1); mx1 = fmaxf(mx1, l1);
        }
        __syncthreads();   // img writes done; reduce arrays free
        r0[t] = mn0; r1[t] = mn1; r2[t] = mx0; r3[t] = mx1;
        __syncthreads();
        for (int st = 128; st > 0; st >>= 1) {
            if (t < st) {
                r0[t] = fminf(r0[t], r0[t + st]); r1[t] = fminf(r1[t], r1[t + st]);
                r2[t] = fmaxf(r2[t], r2[t + st]); r3[t] = fmaxf(r3[t], r3[t + st]);
            }
            __syncthreads();
        }
        mn0 = r0[0]; mn1 = r1[0]; mx0 = r2[0]; mx1 = r3[0];
        float nuw = A.nuw[s], nub = A.nub[s];
        const float TWO_PI = 6.28318530717958647692f;
        for (int j = j0 + chunk * 256 + t; j < j1; j += 2048) {
            int p = A.ind[b * NYP + j];
            float l0 = A.loc[((size_t)b * NYP + p) * 2];
            float l1 = A.loc[((size_t)b * NYP + p) * 2 + 1];
            float om0 = (l0 - mn0) / (mx0 - mn0 + 1e-6f) * TWO_PI - PI_F;
            float om1 = (l1 - mn1) / (mx1 - mn1 + 1e-6f) * TWO_PI - PI_F;
            float stepxs, stepxc, stepys, stepyc;
            sincosf(om0, &stepxs, &stepxc);
            sincosf(om1, &stepys, &stepyc);
            float ex_i, ex_r, ey0_i, ey0_r;
            sincosf(-8.f * om0, &ex_i, &ex_r);
            sincosf(-8.f * om1, &ey0_i, &ey0_r);
            float tot = 0.f;
            for (int xx = 0; xx < 17; ++xx) {
                float inr = 0.f, ini = 0.f;
                float eyr = ey0_r, eyi = ey0_i;
                const float2* row = img + xx * 17;
                #pragma unroll
                for (int y = 0; y < 17; ++y) {
                    float2 iv = row[y];
                    inr += iv.x * eyr - iv.y * eyi;
                    ini += iv.x * eyi + iv.y * eyr;
                    float nr = eyr * stepyc - eyi * stepys;
                    eyi = eyr * stepys + eyi * stepyc; eyr = nr;
                }
                tot += ex_r * inr - ex_i * ini;
                float nr = ex_r * stepxc - ex_i * stepxs;
                ex_i = ex_r * stepxs + ex_i * stepxc; ex_r = nr;
            }
            A.xnu[(size_t)b * NYP + p] = (tot * (1.f / 17.f)) * nuw + nub;
        }
        __syncthreads();
    }
}

// ---------------- de3 decoder + final combine with x_nu ----------------
__global__ __launch_bounds__(256) void k_de3(
    const float* __restrict__ Wde3, const float* __restrict__ bde3,
    const float* __restrict__ q, const float* __restrict__ xnu, float* __restrict__ out)
{
    int nbase = blockIdx.x * 4;
    int t = threadIdx.x;
    float acc[16];
    #pragma unroll
    for (int k = 0; k < 16; ++k) acc[k] = 0.f;
    for (int g4 = t; g4 < GG / 4; g4 += 256) {
        float4 qb[4];
        #pragma unroll
        for (int b = 0; b < 4; ++b)
            qb[b] = ((const float4*)(q + (size_t)b * GG))[g4];
        #pragma unroll
        for (int r = 0; r < 4; ++r) {
            float4 w = ((const float4*)(Wde3 + (size_t)(nbase + r) * GG))[g4];
            #pragma unroll
            for (int b = 0; b < 4; ++b)
                acc[r*4+b] += w.x*qb[b].x + w.y*qb[b].y + w.z*qb[b].z + w.w*qb[b].w;
        }
    }
    #pragma unroll
    for (int k = 0; k < 16; ++k)
        for (int off = 32; off > 0; off >>= 1) acc[k] += __shfl_down(acc[k], off);
    __shared__ float red[4][16];
    int wave = t >> 6, lane = t & 63;
    if (lane == 0) {
        #pragma unroll
        for (int k = 0; k < 16; ++k) red[wave][k] = acc[k];
    }
    __syncthreads();
    if (t < 16) {
        float v = red[0][t] + red[1][t] + red[2][t] + red[3][t];
        int r = t >> 2, b = t & 3;
        int n = nbase + r;
        out[(size_t)b * NYP + n] = v + bde3[n] + xnu[(size_t)b * NYP + n];
    }
}

extern "C" void kernel_launch(void* const* d_in, const int* in_sizes, int n_in,
                              void* d_out, int out_size, void* d_ws, size_t ws_size,
                              hipStream_t stream) {
    const float* x    = (const float*)d_in[0];
    const float* loc  = (const float*)d_in[1];
    const int*   ind  = (const int*)d_in[2];
    const int*   sep  = (const int*)d_in[3];
    const float* We1  = (const float*)d_in[4];
    const float* be1  = (const float*)d_in[5];
    const float* We2  = (const float*)d_in[6];
    const float* be2  = (const float*)d_in[7];
    const float* Wfc0 = (const float*)d_in[8];
    const float* bfc0 = (const float*)d_in[9];
    const float* cw1  = (const float*)d_in[10];
    const float* cw2  = (const float*)d_in[11];
    const float* wpt  = (const float*)d_in[12];
    const float* wptb = (const float*)d_in[13];
    const float* nw1  = (const float*)d_in[14];
    const float* nw2  = (const float*)d_in[15];
    const float* nuw  = (const float*)d_in[16];
    const float* nub  = (const float*)d_in[17];
    const float* Wde3 = (const float*)d_in[18];
    const float* bde3 = (const float*)d_in[19];
    const float* Wfc1 = (const float*)d_in[20];
    const float* bfc1 = (const float*)d_in[21];
    const float* Wfc2 = (const float*)d_in[22];
    const float* bfc2 = (const float*)d_in[23];
    float* out = (float*)d_out;

    float* ws   = (float*)d_ws;
    float* part = ws;                    // 81920
    float* hA   = part + 81920;          // 524288
    float* hB   = hA + 524288;           // 524288
    float* s1u  = hB + 524288;           // 147456
    float* xfg  = s1u + 147456;          // 32768
    float* sofg = xfg + 32768;           // 32768
    float* Fmb  = sofg + 32768;          // 39168
    float* im1g = Fmb + 39168;           // 17408
    float* im2g = im1g + 17408;          // 1152
    float* q    = im2g + 1152;           // 16384
    float* xnu  = q + 16384;             // 32768

    k_embed_part<<<3072, 256, 0, stream>>>(x, loc, We1, We2, part);

    CoopArgs ca;
    ca.part = part; ca.be1 = be1; ca.be2 = be2; ca.Wfc0 = Wfc0; ca.bfc0 = bfc0;
    ca.cw1 = cw1; ca.cw2 = cw2; ca.wpt = wpt; ca.wptb = wptb;
    ca.nw1 = nw1; ca.nw2 = nw2; ca.nuw = nuw; ca.nub = nub;
    ca.loc = loc; ca.Wfc1 = Wfc1; ca.bfc1 = bfc1; ca.Wfc2 = Wfc2; ca.bfc2 = bfc2;
    ca.ind = ind; ca.sep = sep;
    ca.bufA = hA; ca.bufB = hB; ca.s1u = s1u; ca.xfg = xfg; ca.sofg = sofg;
    ca.Fmb = Fmb; ca.im1g = im1g; ca.im2g = im2g; ca.q = q; ca.xnu = xnu;
    void* kargs[] = { &ca };
    hipLaunchCooperativeKernel(k_coop, dim3(CB), dim3(CT), kargs, 0, stream);

    k_de3<<<NYP / 4, 256, 0, stream>>>(Wde3, bde3, q, xnu, out);
}